// Round 2
// baseline (910.524 us; speedup 1.0000x reference)
//
#include <hip/hip_runtime.h>
#include <math.h>

#define F_IN 256
#define CH   16
#define NL   7

#define BS    128         // nodes per bucket (dL fits 7 bits)
#define CHE   8192        // edges per scatter chunk
#define MAXNB 1024        // LDS cap for bucket arrays (NB=782 actual)

// ---------------------------------------------------------------- chunk histogram: H[c][b] = #edges of chunk c with dst in bucket b
__global__ __launch_bounds__(256) void k_hist(const int* __restrict__ dst, int E, int NB,
                                              int* __restrict__ H) {
    __shared__ int h[MAXNB];
    int c = blockIdx.x, tid = threadIdx.x;
    for (int i = tid; i < NB; i += 256) h[i] = 0;
    __syncthreads();
    int beg = c * CHE, end = min(beg + CHE, E);
    for (int e = beg + tid; e < end; e += 256) atomicAdd(&h[dst[e] >> 7], 1);
    __syncthreads();
    int* Hrow = H + (size_t)c * NB;
    for (int i = tid; i < NB; i += 256) Hrow[i] = h[i];
}

// ---------------------------------------------------------------- column sums: total[b] = sum_c H[c][b]   (coalesced over b)
__global__ __launch_bounds__(256) void k_colsum(const int* __restrict__ H, int NB, int C,
                                                int* __restrict__ total) {
    int b = blockIdx.x * 256 + threadIdx.x;
    if (b >= NB) return;
    int s = 0;
#pragma unroll 8
    for (int c = 0; c < C; ++c) s += H[(size_t)c * NB + b];
    total[b] = s;
}

// ---------------------------------------------------------------- exclusive scan of bucket totals (1 WG, NB<=1024)
__global__ __launch_bounds__(1024) void k_scanbase(const int* __restrict__ total, int NB, int E,
                                                   int* __restrict__ base) {
    __shared__ int sm[1024];
    int t = threadIdx.x;
    int v = (t < NB) ? total[t] : 0;
    sm[t] = v;
    __syncthreads();
    for (int off = 1; off < 1024; off <<= 1) {
        int u = (t >= off) ? sm[t - off] : 0;
        __syncthreads();
        sm[t] += u;
        __syncthreads();
    }
    if (t < NB) base[t] = sm[t] - v;
    if (t == 0) base[NB] = E;
}

// ---------------------------------------------------------------- column scan: H[c][b] <- base[b] + sum_{c'<c} H[c'][b]
__global__ __launch_bounds__(256) void k_colscan(int* __restrict__ H, const int* __restrict__ base,
                                                 int NB, int C) {
    int b = blockIdx.x * 256 + threadIdx.x;
    if (b >= NB) return;
    int run = base[b];
#pragma unroll 8
    for (int c = 0; c < C; ++c) {
        size_t idx = (size_t)c * NB + b;
        int t = H[idx];
        H[idx] = run;
        run += t;
    }
}

// ---------------------------------------------------------------- scatter: LDS-local counting sort per chunk, linear writeout
__global__ __launch_bounds__(256) void k_scatter2(const int* __restrict__ src, const int* __restrict__ dst,
                                                  int E, int NB, const int* __restrict__ H,
                                                  int* __restrict__ packed) {
    __shared__ int lcur[MAXNB];   // local exclusive base, then running cursor
    __shared__ int ldel[MAXNB];   // global base - local base
    __shared__ int ssc[256];
    __shared__ int lval[CHE];
    __shared__ int lgs[CHE];
    int c = blockIdx.x, tid = threadIdx.x;
    int beg = c * CHE, end = min(beg + CHE, E), n = end - beg;

    for (int i = tid; i < NB; i += 256) lcur[i] = 0;
    __syncthreads();
    for (int e = beg + tid; e < end; e += 256) atomicAdd(&lcur[dst[e] >> 7], 1);
    __syncthreads();

    // exclusive scan of lcur[0..NB) ; 4 elements per thread
    int i0 = 4 * tid;
    int a0 = (i0 + 0 < NB) ? lcur[i0 + 0] : 0;
    int a1 = (i0 + 1 < NB) ? lcur[i0 + 1] : 0;
    int a2 = (i0 + 2 < NB) ? lcur[i0 + 2] : 0;
    int a3 = (i0 + 3 < NB) ? lcur[i0 + 3] : 0;
    int tsum = a0 + a1 + a2 + a3;
    ssc[tid] = tsum;
    __syncthreads();
    for (int off = 1; off < 256; off <<= 1) {
        int u = (tid >= off) ? ssc[tid - off] : 0;
        __syncthreads();
        ssc[tid] += u;
        __syncthreads();
    }
    int ex = ssc[tid] - tsum;
    __syncthreads();
    if (i0 + 0 < NB) lcur[i0 + 0] = ex;
    if (i0 + 1 < NB) lcur[i0 + 1] = ex + a0;
    if (i0 + 2 < NB) lcur[i0 + 2] = ex + a0 + a1;
    if (i0 + 3 < NB) lcur[i0 + 3] = ex + a0 + a1 + a2;
    __syncthreads();

    const int* Hrow = H + (size_t)c * NB;
    for (int i = tid; i < NB; i += 256) ldel[i] = Hrow[i] - lcur[i];
    __syncthreads();

    // place edges into LDS in bucket-sorted local order, remember global slot
    for (int e = beg + tid; e < end; e += 256) {
        int d = dst[e], s = src[e];
        int b = d >> 7;
        int p = atomicAdd(&lcur[b], 1);
        lval[p] = s | ((d & (BS - 1)) << 17);
        lgs[p]  = ldel[b] + p;
    }
    __syncthreads();

    // linear writeout: consecutive p -> consecutive global slots within runs
    for (int p = tid; p < n; p += 256) packed[lgs[p]] = lval[p];
}

// ---------------------------------------------------------------- dinv from bucketed edges (replaces global atomic degree)
__global__ __launch_bounds__(256) void k_dinv(const int* __restrict__ packed, const int* __restrict__ base,
                                              int N, float* __restrict__ dinv) {
    __shared__ int cnt[BS];
    int b = blockIdx.x, tid = threadIdx.x;
    if (tid < BS) cnt[tid] = 0;
    __syncthreads();
    int beg = base[b], end = base[b + 1];
    for (int e = beg + tid; e < end; e += 256) atomicAdd(&cnt[(packed[e] >> 17) & (BS - 1)], 1);
    __syncthreads();
    int node = b * BS + tid;
    if (tid < BS && node < N) dinv[node] = rsqrtf((float)(cnt[tid] + 1));
}

// ---------------------------------------------------------------- gemm1: g = (x @ W0) * dinv
__global__ __launch_bounds__(256) void k_gemm1(const float* __restrict__ x,
                                               const float* __restrict__ W0,
                                               const float* __restrict__ dinv,
                                               float* __restrict__ g, int N) {
    int lane = threadIdx.x & 63;
    int q = lane >> 4;
    int c = lane & 15;
    float w[64];
#pragma unroll
    for (int t = 0; t < 64; ++t) w[t] = W0[(q * 64 + t) * CH + c];

    int wave  = (blockIdx.x * blockDim.x + threadIdx.x) >> 6;
    int nwave = (gridDim.x * blockDim.x) >> 6;
    for (int row = wave; row < N; row += nwave) {
        const float4* xp = (const float4*)(x + row * F_IN + q * 64);
        float acc = 0.f;
#pragma unroll
        for (int t = 0; t < 16; ++t) {
            float4 v = xp[t];
            acc += v.x * w[4*t] + v.y * w[4*t+1] + v.z * w[4*t+2] + v.w * w[4*t+3];
        }
        acc += __shfl_xor(acc, 16);
        acc += __shfl_xor(acc, 32);
        if (q == 0) g[row * CH + c] = acc * dinv[row];
    }
}

// ---------------------------------------------------------------- agg1: per-bucket LDS accumulate + relu + W1 + dinv
__global__ __launch_bounds__(256) void k_agg1(const float* __restrict__ g,
                                              const int* __restrict__ packed,
                                              const int* __restrict__ base,
                                              const float* __restrict__ W1,
                                              const float* __restrict__ dinv,
                                              float* __restrict__ g2, int N) {
    __shared__ float acc[BS * CH];   // 8 KB
    int b = blockIdx.x, tid = threadIdx.x;
    int c = tid & 15;
    for (int i = tid; i < BS * CH; i += 256) acc[i] = 0.f;
    __syncthreads();

    int beg = base[b], end = base[b + 1];
    int er = tid >> 4;   // 0..15
    for (int eb = beg; eb < end; eb += 64) {
        int e0 = eb + er, e1 = e0 + 16, e2 = e0 + 32, e3 = e0 + 48;
        int v0 = 0, v1 = 0, v2 = 0, v3 = 0;
        float x0 = 0.f, x1 = 0.f, x2 = 0.f, x3 = 0.f;
        bool p0 = e0 < end, p1 = e1 < end, p2 = e2 < end, p3 = e3 < end;
        if (p0) { v0 = packed[e0]; x0 = g[(v0 & 0x1FFFF) * CH + c]; }
        if (p1) { v1 = packed[e1]; x1 = g[(v1 & 0x1FFFF) * CH + c]; }
        if (p2) { v2 = packed[e2]; x2 = g[(v2 & 0x1FFFF) * CH + c]; }
        if (p3) { v3 = packed[e3]; x3 = g[(v3 & 0x1FFFF) * CH + c]; }
        if (p0) atomicAdd(&acc[((v0 >> 17) & (BS - 1)) * CH + c], x0);
        if (p1) atomicAdd(&acc[((v1 >> 17) & (BS - 1)) * CH + c], x1);
        if (p2) atomicAdd(&acc[((v2 >> 17) & (BS - 1)) * CH + c], x2);
        if (p3) atomicAdd(&acc[((v3 >> 17) & (BS - 1)) * CH + c], x3);
    }
    __syncthreads();

    // finalize 16 nodes per iteration
    float w1[NL];
#pragma unroll
    for (int j = 0; j < NL; ++j) w1[j] = W1[c * NL + j];
    int nSub = tid >> 4;
    for (int k = 0; k < BS; k += 16) {
        int nL = k + nSub;
        int node = b * BS + nL;
        if (node < N) {
            float dv = dinv[node];
            float h = fmaxf((acc[nL * CH + c] + g[node * CH + c]) * dv, 0.f);
            float y = 0.f;
#pragma unroll
            for (int j = 0; j < NL; ++j) {
                float p = h * w1[j];
                p += __shfl_xor(p, 8, 16);
                p += __shfl_xor(p, 4, 16);
                p += __shfl_xor(p, 2, 16);
                p += __shfl_xor(p, 1, 16);
                if (c == j) y = p;
            }
            if (c < 8) g2[node * 8 + c] = (c < NL) ? y * dv : 0.f;
        }
    }
}

// ---------------------------------------------------------------- agg2: per-bucket LDS accumulate + exp epilogue
__global__ __launch_bounds__(256) void k_agg2(const float* __restrict__ g2,
                                              const int* __restrict__ packed,
                                              const int* __restrict__ base,
                                              const float* __restrict__ dinv,
                                              float* __restrict__ out, int N) {
    __shared__ float acc[BS * 8];    // 4 KB
    int b = blockIdx.x, tid = threadIdx.x;
    int j = tid & 7;
    for (int i = tid; i < BS * 8; i += 256) acc[i] = 0.f;
    __syncthreads();

    int beg = base[b], end = base[b + 1];
    int er = tid >> 3;   // 0..31
    for (int eb = beg; eb < end; eb += 128) {
        int e0 = eb + er, e1 = e0 + 32, e2 = e0 + 64, e3 = e0 + 96;
        int v0 = 0, v1 = 0, v2 = 0, v3 = 0;
        float x0 = 0.f, x1 = 0.f, x2 = 0.f, x3 = 0.f;
        bool p0 = e0 < end, p1 = e1 < end, p2 = e2 < end, p3 = e3 < end;
        if (p0) { v0 = packed[e0]; x0 = g2[(v0 & 0x1FFFF) * 8 + j]; }
        if (p1) { v1 = packed[e1]; x1 = g2[(v1 & 0x1FFFF) * 8 + j]; }
        if (p2) { v2 = packed[e2]; x2 = g2[(v2 & 0x1FFFF) * 8 + j]; }
        if (p3) { v3 = packed[e3]; x3 = g2[(v3 & 0x1FFFF) * 8 + j]; }
        if (p0) atomicAdd(&acc[((v0 >> 17) & (BS - 1)) * 8 + j], x0);
        if (p1) atomicAdd(&acc[((v1 >> 17) & (BS - 1)) * 8 + j], x1);
        if (p2) atomicAdd(&acc[((v2 >> 17) & (BS - 1)) * 8 + j], x2);
        if (p3) atomicAdd(&acc[((v3 >> 17) & (BS - 1)) * 8 + j], x3);
    }
    __syncthreads();

    int nSub = tid >> 3;
    for (int k = 0; k < BS; k += 32) {
        int nL = k + nSub;
        int node = b * BS + nL;
        if (node < N && j < NL) {
            float dv = dinv[node];
            out[node * NL + j] = __expf((acc[nL * 8 + j] + g2[node * 8 + j]) * dv) + 1.0f;
        }
    }
}

extern "C" void kernel_launch(void* const* d_in, const int* in_sizes, int n_in,
                              void* d_out, int out_size, void* d_ws, size_t ws_size,
                              hipStream_t stream) {
    const float* x  = (const float*)d_in[0];
    const float* W0 = (const float*)d_in[1];
    const float* W1 = (const float*)d_in[2];
    const int*   ei = (const int*)d_in[3];

    const int N = in_sizes[0] / F_IN;       // 100000
    const int E = in_sizes[3] / 2;          // 3200000
    const int* src = ei;
    const int* dst = ei + E;

    const int NB = (N + BS - 1) / BS;       // 782
    const int C  = (E + CHE - 1) / CHE;     // 391

    // workspace (ints/floats, ~24.2 MB):
    // H[C*NB] | base[NB+1] | total[NB] | pad | packed[E] | dinv[N] | g[N*16] | g2[N*8]
    int* H      = (int*)d_ws;
    int* base   = H + (size_t)C * NB;
    int* total  = base + (NB + 1);
    int* packed = total + NB + 64;
    float* dinv = (float*)(packed + E);
    float* g    = dinv + N;
    float* g2   = g + (size_t)N * CH;

    float* out = (float*)d_out;

    // 1) per-chunk bucket histograms (no global atomics anywhere in the sort)
    k_hist<<<C, 256, 0, stream>>>(dst, E, NB, H);

    // 2) bucket bases: column sums -> exclusive scan -> column scan to absolute offsets
    k_colsum<<<(NB + 255) / 256, 256, 0, stream>>>(H, NB, C, total);
    k_scanbase<<<1, 1024, 0, stream>>>(total, NB, E, base);
    k_colscan<<<(NB + 255) / 256, 256, 0, stream>>>(H, base, NB, C);

    // 3) chunked counting-sort scatter (coalesced writeout)
    k_scatter2<<<C, 256, 0, stream>>>(src, dst, E, NB, H, packed);

    // 4) dinv from bucketed edges (replaces 3.2M-atomic k_degree)
    k_dinv<<<NB, 256, 0, stream>>>(packed, base, N, dinv);

    // 5) g = (x@W0) * dinv
    k_gemm1<<<2048, 256, 0, stream>>>(x, W0, dinv, g, N);

    // 6) layer1: per-bucket LDS aggregate + relu + W1 + dinv
    k_agg1<<<NB, 256, 0, stream>>>(g, packed, base, W1, dinv, g2, N);

    // 7) layer2: per-bucket LDS aggregate + exp epilogue
    k_agg2<<<NB, 256, 0, stream>>>(g2, packed, base, dinv, out, N);
}

// Round 4
// 869.537 us; speedup vs baseline: 1.0471x; 1.0471x over previous
//
#include <hip/hip_runtime.h>
#include <math.h>

#define F_IN 256
#define CH   16
#define NL   7

#define BS    64          // nodes per bucket (dL fits 6 bits)
#define CHE   8192        // edges per scatter chunk
#define MAXNB 2048        // LDS cap for bucket arrays (NB=1563 actual)

// ---------------------------------------------------------------- chunk histogram: H[c][b] = #edges of chunk c with dst in bucket b
__global__ __launch_bounds__(256) void k_hist(const int* __restrict__ dst, int E, int NB,
                                              int* __restrict__ H) {
    __shared__ int h[MAXNB];
    int c = blockIdx.x, tid = threadIdx.x;
    for (int i = tid; i < NB; i += 256) h[i] = 0;
    __syncthreads();
    int beg = c * CHE, end = min(beg + CHE, E);
    for (int e = beg + tid; e < end; e += 256) atomicAdd(&h[dst[e] >> 6], 1);
    __syncthreads();
    int* Hrow = H + (size_t)c * NB;
    for (int i = tid; i < NB; i += 256) Hrow[i] = h[i];
}

// ---------------------------------------------------------------- column sums: total[b] = sum_c H[c][b]
__global__ __launch_bounds__(256) void k_colsum(const int* __restrict__ H, int NB, int C,
                                                int* __restrict__ total) {
    int b = blockIdx.x * 256 + threadIdx.x;
    if (b >= NB) return;
    int s = 0;
#pragma unroll 8
    for (int c = 0; c < C; ++c) s += H[(size_t)c * NB + b];
    total[b] = s;
}

// ---------------------------------------------------------------- exclusive scan of bucket totals (1 WG, 2/thread, NB<=2048)
__global__ __launch_bounds__(1024) void k_scanbase(const int* __restrict__ total, int NB, int E,
                                                   int* __restrict__ base) {
    __shared__ int sm[1024];
    int t = threadIdx.x;
    int i0 = 2 * t, i1 = 2 * t + 1;
    int v0 = (i0 < NB) ? total[i0] : 0;
    int v1 = (i1 < NB) ? total[i1] : 0;
    sm[t] = v0 + v1;
    __syncthreads();
    for (int off = 1; off < 1024; off <<= 1) {
        int u = (t >= off) ? sm[t - off] : 0;
        __syncthreads();
        sm[t] += u;
        __syncthreads();
    }
    int ex = sm[t] - (v0 + v1);
    if (i0 < NB) base[i0] = ex;
    if (i1 < NB) base[i1] = ex + v0;
    if (t == 0) base[NB] = E;
}

// ---------------------------------------------------------------- column scan: H[c][b] <- base[b] + sum_{c'<c} H[c'][b]
__global__ __launch_bounds__(256) void k_colscan(int* __restrict__ H, const int* __restrict__ base,
                                                 int NB, int C) {
    int b = blockIdx.x * 256 + threadIdx.x;
    if (b >= NB) return;
    int run = base[b];
#pragma unroll 8
    for (int c = 0; c < C; ++c) {
        size_t idx = (size_t)c * NB + b;
        int t = H[idx];
        H[idx] = run;
        run += t;
    }
}

// ---------------------------------------------------------------- scatter: LDS-local counting sort per chunk, linear writeout
// bucket of each element recovered at writeout via binary search over final cursors
__global__ __launch_bounds__(256) void k_scatter2(const int* __restrict__ src, const int* __restrict__ dst,
                                                  int E, int NB, const int* __restrict__ H,
                                                  int* __restrict__ packed) {
    __shared__ int lcur[MAXNB];   // exclusive starts, then running cursors (final = ends)
    __shared__ int ldel[MAXNB];   // global base - local start
    __shared__ int ssc[256];
    __shared__ int lval[CHE];
    int c = blockIdx.x, tid = threadIdx.x;
    int beg = c * CHE, end = min(beg + CHE, E), n = end - beg;

    for (int i = tid; i < NB; i += 256) lcur[i] = 0;
    __syncthreads();
    for (int e = beg + tid; e < end; e += 256) atomicAdd(&lcur[dst[e] >> 6], 1);
    __syncthreads();

    // exclusive scan of lcur[0..NB), 8 elements per thread
    int i0 = 8 * tid;
    int a[8], tsum = 0;
#pragma unroll
    for (int k = 0; k < 8; ++k) { a[k] = (i0 + k < NB) ? lcur[i0 + k] : 0; tsum += a[k]; }
    ssc[tid] = tsum;
    __syncthreads();
    for (int off = 1; off < 256; off <<= 1) {
        int u = (tid >= off) ? ssc[tid - off] : 0;
        __syncthreads();
        ssc[tid] += u;
        __syncthreads();
    }
    int run = ssc[tid] - tsum;
    __syncthreads();
#pragma unroll
    for (int k = 0; k < 8; ++k) {
        if (i0 + k < NB) lcur[i0 + k] = run;
        run += a[k];
    }
    __syncthreads();

    const int* Hrow = H + (size_t)c * NB;
    for (int i = tid; i < NB; i += 256) ldel[i] = Hrow[i] - lcur[i];
    __syncthreads();

    // place edges into LDS in bucket-sorted local order
    for (int e = beg + tid; e < end; e += 256) {
        int d = dst[e], s = src[e];
        int b = d >> 6;
        int p = atomicAdd(&lcur[b], 1);
        lval[p] = s | ((d & (BS - 1)) << 17);
    }
    __syncthreads();

    // linear writeout; bucket of p = first b with end[b] > p (lcur now holds ends)
    for (int p = tid; p < n; p += 256) {
        int lo = 0, hi = NB - 1;
        while (lo < hi) {
            int mid = (lo + hi) >> 1;
            if (lcur[mid] > p) hi = mid; else lo = mid + 1;
        }
        if (lo > NB - 1) lo = NB - 1;
        packed[ldel[lo] + p] = lval[p];
    }
}

// ---------------------------------------------------------------- dinv from bucketed edges
__global__ __launch_bounds__(256) void k_dinv(const int* __restrict__ packed, const int* __restrict__ base,
                                              int N, float* __restrict__ dinv) {
    __shared__ int cnt[BS];
    int b = blockIdx.x, tid = threadIdx.x;
    if (tid < BS) cnt[tid] = 0;
    __syncthreads();
    int beg = base[b], end = base[b + 1];
    for (int e = beg + tid; e < end; e += 256) atomicAdd(&cnt[(packed[e] >> 17) & (BS - 1)], 1);
    __syncthreads();
    int node = b * BS + tid;
    if (tid < BS && node < N) dinv[node] = rsqrtf((float)(cnt[tid] + 1));
}

// ---------------------------------------------------------------- gemm1: g = (x @ W0) * dinv
__global__ __launch_bounds__(256) void k_gemm1(const float* __restrict__ x,
                                               const float* __restrict__ W0,
                                               const float* __restrict__ dinv,
                                               float* __restrict__ g, int N) {
    int lane = threadIdx.x & 63;
    int q = lane >> 4;
    int c = lane & 15;
    float w[64];
#pragma unroll
    for (int t = 0; t < 64; ++t) w[t] = W0[(q * 64 + t) * CH + c];

    int wave  = (blockIdx.x * blockDim.x + threadIdx.x) >> 6;
    int nwave = (gridDim.x * blockDim.x) >> 6;
    for (int row = wave; row < N; row += nwave) {
        const float4* xp = (const float4*)(x + row * F_IN + q * 64);
        float acc = 0.f;
#pragma unroll
        for (int t = 0; t < 16; ++t) {
            float4 v = xp[t];
            acc += v.x * w[4*t] + v.y * w[4*t+1] + v.z * w[4*t+2] + v.w * w[4*t+3];
        }
        acc += __shfl_xor(acc, 16);
        acc += __shfl_xor(acc, 32);
        if (q == 0) g[row * CH + c] = acc * dinv[row];
    }
}

// ---------------------------------------------------------------- agg1: per-bucket LDS accumulate + relu + W1 + dinv
// 16 edge-slots x 16 channels; 8 gathers in flight per thread
__global__ __launch_bounds__(256) void k_agg1(const float* __restrict__ g,
                                              const int* __restrict__ packed,
                                              const int* __restrict__ base,
                                              const float* __restrict__ W1,
                                              const float* __restrict__ dinv,
                                              float* __restrict__ g2, int N) {
    __shared__ float acc[BS * CH];   // 4 KB
    int b = blockIdx.x, tid = threadIdx.x;
    int c = tid & 15;
    int er = tid >> 4;   // 0..15
    for (int i = tid; i < BS * CH; i += 256) acc[i] = 0.f;
    __syncthreads();

    int beg = base[b], end = base[b + 1];
    for (int eb = beg; eb < end; eb += 128) {
        int v[8]; float xv[8]; bool pr[8];
#pragma unroll
        for (int k = 0; k < 8; ++k) {
            int e = eb + k * 16 + er;
            pr[k] = e < end;
            v[k] = pr[k] ? packed[e] : 0;
        }
#pragma unroll
        for (int k = 0; k < 8; ++k)
            xv[k] = pr[k] ? g[(v[k] & 0x1FFFF) * CH + c] : 0.f;
#pragma unroll
        for (int k = 0; k < 8; ++k)
            if (pr[k]) atomicAdd(&acc[((v[k] >> 17) & (BS - 1)) * CH + c], xv[k]);
    }
    __syncthreads();

    // finalize 16 nodes per iteration
    float w1[NL];
#pragma unroll
    for (int j = 0; j < NL; ++j) w1[j] = W1[c * NL + j];
    int nSub = tid >> 4;
    for (int k = 0; k < BS; k += 16) {
        int nL = k + nSub;
        int node = b * BS + nL;
        if (node < N) {
            float dv = dinv[node];
            float h = fmaxf((acc[nL * CH + c] + g[node * CH + c]) * dv, 0.f);
            float y = 0.f;
#pragma unroll
            for (int j = 0; j < NL; ++j) {
                float p = h * w1[j];
                p += __shfl_xor(p, 8, 16);
                p += __shfl_xor(p, 4, 16);
                p += __shfl_xor(p, 2, 16);
                p += __shfl_xor(p, 1, 16);
                if (c == j) y = p;
            }
            if (c < 8) g2[node * 8 + c] = (c < NL) ? y * dv : 0.f;
        }
    }
}

// ---------------------------------------------------------------- agg2: per-bucket LDS accumulate + exp epilogue
// 32 edge-slots x 8 channels; 8 gathers in flight per thread
__global__ __launch_bounds__(256) void k_agg2(const float* __restrict__ g2,
                                              const int* __restrict__ packed,
                                              const int* __restrict__ base,
                                              const float* __restrict__ dinv,
                                              float* __restrict__ out, int N) {
    __shared__ float acc[BS * 8];    // 2 KB
    int b = blockIdx.x, tid = threadIdx.x;
    int j = tid & 7;
    int er = tid >> 3;   // 0..31
    for (int i = tid; i < BS * 8; i += 256) acc[i] = 0.f;
    __syncthreads();

    int beg = base[b], end = base[b + 1];
    for (int eb = beg; eb < end; eb += 256) {
        int v[8]; float xv[8]; bool pr[8];
#pragma unroll
        for (int k = 0; k < 8; ++k) {
            int e = eb + k * 32 + er;
            pr[k] = e < end;
            v[k] = pr[k] ? packed[e] : 0;
        }
#pragma unroll
        for (int k = 0; k < 8; ++k)
            xv[k] = pr[k] ? g2[(v[k] & 0x1FFFF) * 8 + j] : 0.f;
#pragma unroll
        for (int k = 0; k < 8; ++k)
            if (pr[k]) atomicAdd(&acc[((v[k] >> 17) & (BS - 1)) * 8 + j], xv[k]);
    }
    __syncthreads();

    int nSub = tid >> 3;
    for (int k = 0; k < BS; k += 32) {
        int nL = k + nSub;
        int node = b * BS + nL;
        if (node < N && j < NL) {
            float dv = dinv[node];
            out[node * NL + j] = __expf((acc[nL * 8 + j] + g2[node * 8 + j]) * dv) + 1.0f;
        }
    }
}

extern "C" void kernel_launch(void* const* d_in, const int* in_sizes, int n_in,
                              void* d_out, int out_size, void* d_ws, size_t ws_size,
                              hipStream_t stream) {
    const float* x  = (const float*)d_in[0];
    const float* W0 = (const float*)d_in[1];
    const float* W1 = (const float*)d_in[2];
    const int*   ei = (const int*)d_in[3];

    const int N = in_sizes[0] / F_IN;       // 100000
    const int E = in_sizes[3] / 2;          // 3200000
    const int* src = ei;
    const int* dst = ei + E;

    const int NB = (N + BS - 1) / BS;       // 1563
    const int C  = (E + CHE - 1) / CHE;     // 391

    // workspace (~25.3 MB):
    // H[C*NB] | base[NB+1] | total[NB] | pad | packed[E] | dinv[N] | g[N*16] | g2[N*8]
    int* H      = (int*)d_ws;
    int* base   = H + (size_t)C * NB;
    int* total  = base + (NB + 1);
    int* packed = total + NB + 64;
    float* dinv = (float*)(packed + E);
    float* g    = dinv + N;
    float* g2   = g + (size_t)N * CH;

    float* out = (float*)d_out;

    // 1) per-chunk bucket histograms
    k_hist<<<C, 256, 0, stream>>>(dst, E, NB, H);

    // 2) bucket bases
    k_colsum<<<(NB + 255) / 256, 256, 0, stream>>>(H, NB, C, total);
    k_scanbase<<<1, 1024, 0, stream>>>(total, NB, E, base);
    k_colscan<<<(NB + 255) / 256, 256, 0, stream>>>(H, base, NB, C);

    // 3) chunked counting-sort scatter (coalesced writeout, 49 KB LDS -> 3 blocks/CU)
    k_scatter2<<<C, 256, 0, stream>>>(src, dst, E, NB, H, packed);

    // 4) dinv from bucketed edges
    k_dinv<<<NB, 256, 0, stream>>>(packed, base, N, dinv);

    // 5) g = (x@W0) * dinv
    k_gemm1<<<2048, 256, 0, stream>>>(x, W0, dinv, g, N);

    // 6) layer1 aggregate + relu + W1 + dinv
    k_agg1<<<NB, 256, 0, stream>>>(g, packed, base, W1, dinv, g2, N);

    // 7) layer2 aggregate + exp epilogue
    k_agg2<<<NB, 256, 0, stream>>>(g2, packed, base, dinv, out, N);
}

// Round 5
// 835.147 us; speedup vs baseline: 1.0903x; 1.0412x over previous
//
#include <hip/hip_runtime.h>
#include <math.h>

#define F_IN 256
#define CH   16
#define NL   7

#define BS    64          // nodes per bucket (dL fits 6 bits)
#define CHE   8192        // edges per scatter chunk
#define MAXNB 2048        // LDS cap for bucket arrays (NB=1563 actual)

// ---------------------------------------------------------------- chunk histogram: H[c][b] = #edges of chunk c with dst in bucket b
__global__ __launch_bounds__(1024) void k_hist(const int* __restrict__ dst, int E, int NB,
                                               int* __restrict__ H) {
    __shared__ int h[MAXNB];
    int c = blockIdx.x, tid = threadIdx.x;
    for (int i = tid; i < NB; i += 1024) h[i] = 0;
    __syncthreads();
    int beg = c * CHE, end = min(beg + CHE, E);
    for (int e = beg + tid; e < end; e += 1024) atomicAdd(&h[dst[e] >> 6], 1);
    __syncthreads();
    int* Hrow = H + (size_t)c * NB;
    for (int i = tid; i < NB; i += 1024) Hrow[i] = h[i];
}

// ---------------------------------------------------------------- column sums: total[b] = sum_c H[c][b]
__global__ __launch_bounds__(256) void k_colsum(const int* __restrict__ H, int NB, int C,
                                                int* __restrict__ total) {
    int b = blockIdx.x * 256 + threadIdx.x;
    if (b >= NB) return;
    int s = 0;
#pragma unroll 8
    for (int c = 0; c < C; ++c) s += H[(size_t)c * NB + b];
    total[b] = s;
}

// ---------------------------------------------------------------- exclusive scan of bucket totals (1 WG, 2/thread, NB<=2048)
__global__ __launch_bounds__(1024) void k_scanbase(const int* __restrict__ total, int NB, int E,
                                                   int* __restrict__ base) {
    __shared__ int sm[1024];
    int t = threadIdx.x;
    int i0 = 2 * t, i1 = 2 * t + 1;
    int v0 = (i0 < NB) ? total[i0] : 0;
    int v1 = (i1 < NB) ? total[i1] : 0;
    sm[t] = v0 + v1;
    __syncthreads();
    for (int off = 1; off < 1024; off <<= 1) {
        int u = (t >= off) ? sm[t - off] : 0;
        __syncthreads();
        sm[t] += u;
        __syncthreads();
    }
    int ex = sm[t] - (v0 + v1);
    if (i0 < NB) base[i0] = ex;
    if (i1 < NB) base[i1] = ex + v0;
    if (t == 0) base[NB] = E;
}

// ---------------------------------------------------------------- column scan: H[c][b] <- base[b] + sum_{c'<c} H[c'][b]
__global__ __launch_bounds__(256) void k_colscan(int* __restrict__ H, const int* __restrict__ base,
                                                 int NB, int C) {
    int b = blockIdx.x * 256 + threadIdx.x;
    if (b >= NB) return;
    int run = base[b];
#pragma unroll 8
    for (int c = 0; c < C; ++c) {
        size_t idx = (size_t)c * NB + b;
        int t = H[idx];
        H[idx] = run;
        run += t;
    }
}

// ---------------------------------------------------------------- scatter: LDS-local counting sort per chunk, linear writeout
__global__ __launch_bounds__(1024) void k_scatter2(const int* __restrict__ src, const int* __restrict__ dst,
                                                   int E, int NB, const int* __restrict__ H,
                                                   int* __restrict__ packed) {
    __shared__ int lcur[MAXNB];            // exclusive starts, then running cursors
    __shared__ int ldel[MAXNB];            // global base - local start
    __shared__ int ssc[1024];
    __shared__ int lval[CHE];
    __shared__ unsigned short lbkt[CHE];   // bucket id per local slot
    int c = blockIdx.x, tid = threadIdx.x;
    int beg = c * CHE, end = min(beg + CHE, E), n = end - beg;

    for (int i = tid; i < NB; i += 1024) lcur[i] = 0;
    __syncthreads();
    for (int e = beg + tid; e < end; e += 1024) atomicAdd(&lcur[dst[e] >> 6], 1);
    __syncthreads();

    // exclusive scan of lcur[0..NB), 2 elements per thread
    int i0 = 2 * tid;
    int a0 = (i0 < NB) ? lcur[i0] : 0;
    int a1 = (i0 + 1 < NB) ? lcur[i0 + 1] : 0;
    int tsum = a0 + a1;
    ssc[tid] = tsum;
    __syncthreads();
    for (int off = 1; off < 1024; off <<= 1) {
        int u = (tid >= off) ? ssc[tid - off] : 0;
        __syncthreads();
        ssc[tid] += u;
        __syncthreads();
    }
    int ex = ssc[tid] - tsum;
    if (i0 < NB) lcur[i0] = ex;
    if (i0 + 1 < NB) lcur[i0 + 1] = ex + a0;
    __syncthreads();

    const int* Hrow = H + (size_t)c * NB;
    for (int i = tid; i < NB; i += 1024) ldel[i] = Hrow[i] - lcur[i];
    __syncthreads();

    // place edges into LDS in bucket-sorted local order
    for (int e = beg + tid; e < end; e += 1024) {
        int d = dst[e], s = src[e];
        int bb = d >> 6;
        int p = atomicAdd(&lcur[bb], 1);
        lval[p] = s | ((d & (BS - 1)) << 17);
        lbkt[p] = (unsigned short)bb;
    }
    __syncthreads();

    // linear writeout
    for (int p = tid; p < n; p += 1024)
        packed[ldel[lbkt[p]] + p] = lval[p];
}

// ---------------------------------------------------------------- dinv from bucketed edges
__global__ __launch_bounds__(256) void k_dinv(const int* __restrict__ packed, const int* __restrict__ base,
                                              int N, float* __restrict__ dinv) {
    __shared__ int cnt[BS];
    int b = blockIdx.x, tid = threadIdx.x;
    if (tid < BS) cnt[tid] = 0;
    __syncthreads();
    int beg = base[b], end = base[b + 1];
    for (int e = beg + tid; e < end; e += 256) atomicAdd(&cnt[(packed[e] >> 17) & (BS - 1)], 1);
    __syncthreads();
    int node = b * BS + tid;
    if (tid < BS && node < N) dinv[node] = rsqrtf((float)(cnt[tid] + 1));
}

// ---------------------------------------------------------------- gemm1: g = (x @ W0) * dinv, split into 8-ch halves
__global__ __launch_bounds__(256) void k_gemm1(const float* __restrict__ x,
                                               const float* __restrict__ W0,
                                               const float* __restrict__ dinv,
                                               float* __restrict__ gA, float* __restrict__ gB, int N) {
    int lane = threadIdx.x & 63;
    int q = lane >> 4;
    int c = lane & 15;
    float w[64];
#pragma unroll
    for (int t = 0; t < 64; ++t) w[t] = W0[(q * 64 + t) * CH + c];

    int wave  = (blockIdx.x * blockDim.x + threadIdx.x) >> 6;
    int nwave = (gridDim.x * blockDim.x) >> 6;
    for (int row = wave; row < N; row += nwave) {
        const float4* xp = (const float4*)(x + row * F_IN + q * 64);
        float acc = 0.f;
#pragma unroll
        for (int t = 0; t < 16; ++t) {
            float4 v = xp[t];
            acc += v.x * w[4*t] + v.y * w[4*t+1] + v.z * w[4*t+2] + v.w * w[4*t+3];
        }
        acc += __shfl_xor(acc, 16);
        acc += __shfl_xor(acc, 32);
        if (q == 0) {
            float val = acc * dinv[row];
            if (c < 8) gA[row * 8 + c] = val;
            else       gB[row * 8 + (c - 8)] = val;
        }
    }
}

// ---------------------------------------------------------------- agg1 pass A: channels 0-7, gather from L2-resident gA (3.2 MB)
__global__ __launch_bounds__(1024) void k_agg1a(const float* __restrict__ gA,
                                                const int* __restrict__ packed,
                                                const int* __restrict__ base,
                                                float* __restrict__ hpart, int N) {
    __shared__ float acc[BS * 8];    // 2 KB
    int b = blockIdx.x, tid = threadIdx.x;
    int cj = tid & 7, er = tid >> 3; // 0..127
    for (int i = tid; i < BS * 8; i += 1024) acc[i] = 0.f;
    __syncthreads();

    int beg = base[b], end = base[b + 1];
    for (int eb = beg; eb < end; eb += 1024) {
        int v[8]; float xv[8]; bool pr[8];
#pragma unroll
        for (int k = 0; k < 8; ++k) {
            int e = eb + k * 128 + er;
            pr[k] = e < end;
            v[k] = pr[k] ? __builtin_nontemporal_load(packed + e) : 0;
        }
#pragma unroll
        for (int k = 0; k < 8; ++k)
            xv[k] = pr[k] ? gA[(v[k] & 0x1FFFF) * 8 + cj] : 0.f;
#pragma unroll
        for (int k = 0; k < 8; ++k)
            if (pr[k]) atomicAdd(&acc[((v[k] >> 17) & (BS - 1)) * 8 + cj], xv[k]);
    }
    __syncthreads();

    if (tid < BS * 8) {
        int nL = tid >> 3, c = tid & 7;
        int node = b * BS + nL;
        if (node < N)
            __builtin_nontemporal_store(acc[nL * 8 + c] + gA[node * 8 + c],
                                        hpart + (size_t)node * 8 + c);
    }
}

// ---------------------------------------------------------------- agg1 pass B: channels 8-15 + fused relu/W1/dinv epilogue
__global__ __launch_bounds__(1024) void k_agg1b(const float* __restrict__ gB,
                                                const int* __restrict__ packed,
                                                const int* __restrict__ base,
                                                const float* __restrict__ hpart,
                                                const float* __restrict__ W1,
                                                const float* __restrict__ dinv,
                                                float* __restrict__ g2, int N) {
    __shared__ float acc[BS * 8];    // 2 KB
    int b = blockIdx.x, tid = threadIdx.x;
    int cj = tid & 7, er = tid >> 3;
    for (int i = tid; i < BS * 8; i += 1024) acc[i] = 0.f;
    __syncthreads();

    int beg = base[b], end = base[b + 1];
    for (int eb = beg; eb < end; eb += 1024) {
        int v[8]; float xv[8]; bool pr[8];
#pragma unroll
        for (int k = 0; k < 8; ++k) {
            int e = eb + k * 128 + er;
            pr[k] = e < end;
            v[k] = pr[k] ? __builtin_nontemporal_load(packed + e) : 0;
        }
#pragma unroll
        for (int k = 0; k < 8; ++k)
            xv[k] = pr[k] ? gB[(v[k] & 0x1FFFF) * 8 + cj] : 0.f;
#pragma unroll
        for (int k = 0; k < 8; ++k)
            if (pr[k]) atomicAdd(&acc[((v[k] >> 17) & (BS - 1)) * 8 + cj], xv[k]);
    }
    __syncthreads();

    // epilogue: one thread per (node, channel): tid = nL*16 + c
    int c = tid & 15, nL = tid >> 4;     // nL 0..63
    float w1[NL];
#pragma unroll
    for (int j = 0; j < NL; ++j) w1[j] = W1[c * NL + j];
    int node = b * BS + nL;
    if (node < N) {
        float dv = dinv[node];
        float s = (c < 8) ? __builtin_nontemporal_load(hpart + (size_t)node * 8 + c)
                          : (acc[nL * 8 + (c - 8)] + gB[node * 8 + (c - 8)]);
        float h = fmaxf(s * dv, 0.f);
        float y = 0.f;
#pragma unroll
        for (int j = 0; j < NL; ++j) {
            float p = h * w1[j];
            p += __shfl_xor(p, 8, 16);
            p += __shfl_xor(p, 4, 16);
            p += __shfl_xor(p, 2, 16);
            p += __shfl_xor(p, 1, 16);
            if (c == j) y = p;
        }
        if (c < 8) g2[node * 8 + c] = (c < NL) ? y * dv : 0.f;
    }
}

// ---------------------------------------------------------------- agg2: gather from L2-resident g2 (3.2 MB) + exp epilogue
__global__ __launch_bounds__(1024) void k_agg2(const float* __restrict__ g2,
                                               const int* __restrict__ packed,
                                               const int* __restrict__ base,
                                               const float* __restrict__ dinv,
                                               float* __restrict__ out, int N) {
    __shared__ float acc[BS * 8];    // 2 KB
    int b = blockIdx.x, tid = threadIdx.x;
    int j = tid & 7, er = tid >> 3;
    for (int i = tid; i < BS * 8; i += 1024) acc[i] = 0.f;
    __syncthreads();

    int beg = base[b], end = base[b + 1];
    for (int eb = beg; eb < end; eb += 1024) {
        int v[8]; float xv[8]; bool pr[8];
#pragma unroll
        for (int k = 0; k < 8; ++k) {
            int e = eb + k * 128 + er;
            pr[k] = e < end;
            v[k] = pr[k] ? __builtin_nontemporal_load(packed + e) : 0;
        }
#pragma unroll
        for (int k = 0; k < 8; ++k)
            xv[k] = pr[k] ? g2[(v[k] & 0x1FFFF) * 8 + j] : 0.f;
#pragma unroll
        for (int k = 0; k < 8; ++k)
            if (pr[k]) atomicAdd(&acc[((v[k] >> 17) & (BS - 1)) * 8 + j], xv[k]);
    }
    __syncthreads();

    if (tid < BS * 8) {
        int nL = tid >> 3;
        int node = b * BS + nL;
        if (node < N && j < NL) {
            float dv = dinv[node];
            out[(size_t)node * NL + j] = __expf((acc[nL * 8 + j] + g2[node * 8 + j]) * dv) + 1.0f;
        }
    }
}

extern "C" void kernel_launch(void* const* d_in, const int* in_sizes, int n_in,
                              void* d_out, int out_size, void* d_ws, size_t ws_size,
                              hipStream_t stream) {
    const float* x  = (const float*)d_in[0];
    const float* W0 = (const float*)d_in[1];
    const float* W1 = (const float*)d_in[2];
    const int*   ei = (const int*)d_in[3];

    const int N = in_sizes[0] / F_IN;       // 100000
    const int E = in_sizes[3] / 2;          // 3200000
    const int* src = ei;
    const int* dst = ei + E;

    const int NB = (N + BS - 1) / BS;       // 1563
    const int C  = (E + CHE - 1) / CHE;     // 391

    // workspace (~28.5 MB):
    // H[C*NB] | base[NB+1] | total[NB] | pad | packed[E] | dinv[N] | gA[N*8] | gB[N*8] | hpart[N*8] | g2[N*8]
    int* H       = (int*)d_ws;
    int* base    = H + (size_t)C * NB;
    int* total   = base + (NB + 1);
    int* packed  = total + NB + 64;
    float* dinv  = (float*)(packed + E);
    float* gA    = dinv + N;
    float* gB    = gA + (size_t)N * 8;
    float* hpart = gB + (size_t)N * 8;
    float* g2    = hpart + (size_t)N * 8;

    float* out = (float*)d_out;

    // 1) per-chunk bucket histograms
    k_hist<<<C, 1024, 0, stream>>>(dst, E, NB, H);

    // 2) bucket bases
    k_colsum<<<(NB + 255) / 256, 256, 0, stream>>>(H, NB, C, total);
    k_scanbase<<<1, 1024, 0, stream>>>(total, NB, E, base);
    k_colscan<<<(NB + 255) / 256, 256, 0, stream>>>(H, base, NB, C);

    // 3) chunked counting-sort scatter (68 KB LDS, 1024 thr -> 2 blocks/CU = 32 waves)
    k_scatter2<<<C, 1024, 0, stream>>>(src, dst, E, NB, H, packed);

    // 4) dinv from bucketed edges
    k_dinv<<<NB, 256, 0, stream>>>(packed, base, N, dinv);

    // 5) g = (x@W0) * dinv, split into two 3.2 MB halves (each fits per-XCD L2)
    k_gemm1<<<2048, 256, 0, stream>>>(x, W0, dinv, gA, gB, N);

    // 6) layer1 aggregate: two L2-resident passes
    k_agg1a<<<NB, 1024, 0, stream>>>(gA, packed, base, hpart, N);
    k_agg1b<<<NB, 1024, 0, stream>>>(gB, packed, base, hpart, W1, dinv, g2, N);

    // 7) layer2 aggregate + exp epilogue (g2 is 3.2 MB, L2-resident)
    k_agg2<<<NB, 1024, 0, stream>>>(g2, packed, base, dinv, out, N);
}